// Round 13
// baseline (1882.003 us; speedup 1.0000x reference)
//
#include <hip/hip_runtime.h>
#include <float.h>

typedef _Float16 f16;
typedef f16 f16x8 __attribute__((ext_vector_type(8)));
typedef float f32x4 __attribute__((ext_vector_type(4)));
typedef unsigned int u32;

#define NPTS 262144
#define DDIM 128
#define NVQ 6
#define KCODES 512
#define TM 16          // points per block (single wave)
#define BLOCKT 64

__device__ __forceinline__ int swz(int row, int grp) {
    return row * DDIM + ((grp ^ (row & 7)) << 3);
}
__device__ __forceinline__ u32 umin32(u32 a, u32 b) { return a < b ? a : b; }
__device__ __forceinline__ u32 umax32(u32 a, u32 b) { return a > b ? a : b; }

__device__ __forceinline__ f16x8 cvt8(float4 a, float4 b) {
    f16x8 h;
    h[0] = (f16)a.x; h[1] = (f16)a.y; h[2] = (f16)a.z; h[3] = (f16)a.w;
    h[4] = (f16)b.x; h[5] = (f16)b.y; h[6] = (f16)b.z; h[7] = (f16)b.w;
    return h;
}

// ---------------------------------------------------------------------------
__global__ void zero_commit_kernel(float* p) { *p = 0.0f; }

// norms[row] = ||E||^2 exact; ascore[row] = 512 - 0.5*||E||^2 (keeps approx
// scores strictly positive so uint ordering of float bits is valid)
__global__ void norms_kernel(const float* __restrict__ cb, float* __restrict__ norms,
                             float* __restrict__ ascore) {
    int row = blockIdx.x;
    int lane = threadIdx.x;
    const float* r = cb + (size_t)row * DDIM;
    float2 v = *(const float2*)(r + lane * 2);
    float s = v.x * v.x + v.y * v.y;
    #pragma unroll
    for (int m = 32; m >= 1; m >>= 1) s += __shfl_xor(s, m);
    if (lane == 0) { norms[row] = s; ascore[row] = 512.0f - 0.5f * s; }
}

__global__ void preconv_kernel(const float* __restrict__ cb, f16* __restrict__ cb16) {
    size_t base = ((size_t)blockIdx.x * 256 + threadIdx.x) * 8;
    float4 a = *(const float4*)(cb + base);
    float4 b = *(const float4*)(cb + base + 4);
    *(f16x8*)(cb16 + base) = cvt8(a, b);
}

// ---------------------------------------------------------------------------
// Residual VQ — SINGLE-WAVE blocks (TM=16). Rounds 6-12 evidence: the 4-wave
// barrier-coupled block keeps waves in lockstep (62-73% no-issue at any
// occupancy/register mix). Here each wave owns 16 points end-to-end:
//  - per chunk: D[64 codes x 16 pts], A = 4 code subtiles (L2 stream),
//    B = the wave's own 4 point-fragments (16 regs, was 64)
//  - top-2 state = 2 regs (u32 keys, all distinct -> merge-order-free)
//  - NO cross-wave merge, no cand LDS; __syncthreads on a 1-wave block is
//    immediate -> blocks fully desynced (setprio regime)
//  - live set ~95 arch + 16 agpr fits waves_per_eu(4,4) budget (128 total)
//    -> 4 waves/SIMD spill-free (unreachable with the 4-wave structure)
// SELECTION IS BIT-IDENTICAL to r11 (passing, absmax 5.421875): same
// ks=0,1,2,3 MFMA chains, same fragments, distinct keys, same rescue
// summation tree (xor16/32 replaces xor1/2 — same ((q0+q1)+(q2+q3)) shape).
// FP ORDER FROZEN (r8/r9 lesson).
template<bool PRE>
__global__ __launch_bounds__(BLOCKT)
__attribute__((amdgpu_waves_per_eu(4, 4)))
void rvq_kernel(const float* __restrict__ x, const float* __restrict__ cb,
                const f16* __restrict__ cb16, const float* __restrict__ W,
                const float* __restrict__ bias, const float* __restrict__ norms,
                const float* __restrict__ ascore, float* __restrict__ out) {
    __shared__ f16 rh[TM * DDIM];   // 4 KB residual/y fp16, swizzled

    const int lane = threadIdx.x;   // 0..63
    const int g    = lane >> 4;     // k-group / quarter 0..3
    const int li   = lane & 15;     // point within tile
    const int p0   = blockIdx.x * TM;

    // ---- x -> r (regs, quarter g of point li) and rh (fp16 LDS) ----
    float r[32];
    {
        const float* xs = x + (size_t)(p0 + li) * DDIM + g * 32;
        #pragma unroll
        for (int k = 0; k < 8; ++k) {
            float4 v = *(const float4*)(xs + 4 * k);
            r[4*k] = v.x; r[4*k+1] = v.y; r[4*k+2] = v.z; r[4*k+3] = v.w;
        }
    }
    #pragma unroll
    for (int k = 0; k < 4; ++k) {
        f16x8 h;
        #pragma unroll
        for (int m = 0; m < 8; ++m) h[m] = (f16)r[8*k+m];
        *(f16x8*)&rh[swz(li, g * 4 + k)] = h;
    }
    __syncthreads();   // 1-wave: immediate; orders LDS

    float commit_part = 0.0f;

    #pragma unroll 1
    for (int s = 0; s < NVQ; ++s) {
        // ---- B fragments: the wave's own points (16 regs) ----
        f16x8 Bf[4];
        #pragma unroll
        for (int ks = 0; ks < 4; ++ks)
            Bf[ks] = *(const f16x8*)&rh[swz(li, ks * 4 + g)];

        u32 k1 = 0u, k2 = 0u;

        const f16*   Ab   = cb16 + ((size_t)s * KCODES + li) * DDIM + g * 8;
        const float* Ab32 = cb   + ((size_t)s * KCODES + li) * DDIM + g * 8;
        const float* asb  = ascore + s * KCODES + 4 * g;

        #pragma unroll 1
        for (int ch = 0; ch < 8; ++ch) {
            f32x4 acc[4];
            #pragma unroll
            for (int i = 0; i < 4; ++i) acc[i] = (f32x4)0.0f;

            __builtin_amdgcn_s_setprio(1);
            // FP order frozen: each acc[i] accumulates ks = 0,1,2,3.
            #pragma unroll
            for (int ks = 0; ks < 4; ++ks) {
                #pragma unroll
                for (int i = 0; i < 4; ++i) {
                    f16x8 Af;
                    if (PRE) {
                        Af = *(const f16x8*)(Ab + (size_t)(ch * 64 + 16 * i) * DDIM + ks * 32);
                    } else {
                        const float* ap = Ab32 + (size_t)(ch * 64 + 16 * i) * DDIM + ks * 32;
                        Af = cvt8(*(const float4*)ap, *(const float4*)(ap + 4));
                    }
                    acc[i] = __builtin_amdgcn_mfma_f32_16x16x32_f16(Af, Bf[ks], acc[i], 0, 0, 0);
                }
            }
            __builtin_amdgcn_s_setprio(0);

            #pragma unroll
            for (int i = 0; i < 4; ++i) {
                float4 as4 = *(const float4*)(asb + ch * 64 + 16 * i);
                const int invc = 511 - (ch * 64 + 16 * i + 4 * g);
                #pragma unroll
                for (int reg = 0; reg < 4; ++reg) {
                    float sc = acc[i][reg] +
                        ((reg == 0) ? as4.x : (reg == 1) ? as4.y : (reg == 2) ? as4.z : as4.w);
                    u32 key = (__float_as_uint(sc) & 0xFFFFFE00u) | (u32)(invc - reg);
                    u32 lo = umin32(k1, key);
                    k1 = umax32(k1, key);
                    k2 = umax32(k2, lo);
                }
            }
        }

        // ---- in-wave top-2 butterfly across the 4 g-groups (xor 16, 32) ----
        #pragma unroll
        for (int m = 16; m <= 32; m <<= 1) {
            u32 o1 = (u32)__shfl_xor((int)k1, m);
            u32 o2 = (u32)__shfl_xor((int)k2, m);
            u32 lo = umin32(k1, o1);
            k1 = umax32(k1, o1);
            k2 = umax32(umax32(k2, o2), lo);
        }
        int c1 = 511 - (int)(k1 & 0x1FFu);
        int c2 = 511 - (int)(k2 & 0x1FFu);

        // ---- exact fp32 rescue on top-2 (quarter g; same summation tree) ----
        const float* E1 = cb + (size_t)(s * KCODES + c1) * DDIM + g * 32;
        const float* E2 = cb + (size_t)(s * KCODES + c2) * DDIM + g * 32;
        float dot1 = 0.0f, dot2 = 0.0f;
        #pragma unroll
        for (int k = 0; k < 8; ++k) {
            float4 a = *(const float4*)(E1 + 4 * k);
            dot1 += a.x * r[4*k] + a.y * r[4*k+1] + a.z * r[4*k+2] + a.w * r[4*k+3];
        }
        #pragma unroll
        for (int k = 0; k < 8; ++k) {
            float4 a = *(const float4*)(E2 + 4 * k);
            dot2 += a.x * r[4*k] + a.y * r[4*k+1] + a.z * r[4*k+2] + a.w * r[4*k+3];
        }
        dot1 += __shfl_xor(dot1, 16); dot1 += __shfl_xor(dot1, 32);
        dot2 += __shfl_xor(dot2, 16); dot2 += __shfl_xor(dot2, 32);
        float d1e = fmaf(-2.0f, dot1, norms[s * KCODES + c1]);
        float d2e = fmaf(-2.0f, dot2, norms[s * KCODES + c2]);
        int best = (d2e < d1e || (d2e == d1e && c2 < c1)) ? c2 : c1;

        if (s == 0 && g == 0)
            out[(size_t)NPTS * DDIM + p0 + li] = (float)best;

        // ---- exact residual update (regs) + rh rewrite for next stage ----
        {
            const float* Eb = cb + (size_t)(s * KCODES + best) * DDIM + g * 32;
            float cp = 0.0f;
            #pragma unroll
            for (int k = 0; k < 8; ++k) {
                float4 e = *(const float4*)(Eb + 4 * k);
                r[4*k]   -= e.x; r[4*k+1] -= e.y; r[4*k+2] -= e.z; r[4*k+3] -= e.w;
                cp += r[4*k]*r[4*k] + r[4*k+1]*r[4*k+1] + r[4*k+2]*r[4*k+2] + r[4*k+3]*r[4*k+3];
            }
            if (s == 0) commit_part = cp;
        }
        if (s < NVQ - 1) {
            #pragma unroll
            for (int k = 0; k < 4; ++k) {
                f16x8 h;
                #pragma unroll
                for (int m = 0; m < 8; ++m) h[m] = (f16)r[8*k+m];
                *(f16x8*)&rh[swz(li, g * 4 + k)] = h;
            }
        }
        __syncthreads();   // 1-wave: immediate
    }

    // ---- y = x - r_final -> rh ----
    {
        const float* xs = x + (size_t)(p0 + li) * DDIM + g * 32;
        #pragma unroll
        for (int k = 0; k < 4; ++k) {
            float4 a = *(const float4*)(xs + 8 * k);
            float4 b = *(const float4*)(xs + 8 * k + 4);
            f16x8 h;
            h[0]=(f16)(a.x - r[8*k+0]); h[1]=(f16)(a.y - r[8*k+1]);
            h[2]=(f16)(a.z - r[8*k+2]); h[3]=(f16)(a.w - r[8*k+3]);
            h[4]=(f16)(b.x - r[8*k+4]); h[5]=(f16)(b.y - r[8*k+5]);
            h[6]=(f16)(b.z - r[8*k+6]); h[7]=(f16)(b.w - r[8*k+7]);
            *(f16x8*)&rh[swz(li, g * 4 + k)] = h;
        }
    }
    __syncthreads();   // 1-wave: immediate

    // ---- final linear: out = y @ W^T + b (W rows streamed from global) ----
    {
        f16x8 Yf[4];
        #pragma unroll
        for (int ks = 0; ks < 4; ++ks)
            Yf[ks] = *(const f16x8*)&rh[swz(li, ks * 4 + g)];

        #pragma unroll 1
        for (int ch = 0; ch < 2; ++ch) {
            f32x4 acc[4];
            #pragma unroll
            for (int i = 0; i < 4; ++i) {
                float4 b4 = *(const float4*)(bias + ch * 64 + 16 * i + 4 * g);
                acc[i][0] = b4.x; acc[i][1] = b4.y; acc[i][2] = b4.z; acc[i][3] = b4.w;
            }
            __builtin_amdgcn_s_setprio(1);
            #pragma unroll
            for (int ks = 0; ks < 4; ++ks) {
                #pragma unroll
                for (int i = 0; i < 4; ++i) {
                    const float* wp = W + (size_t)(ch * 64 + 16 * i + li) * DDIM + ks * 32 + g * 8;
                    f16x8 Af = cvt8(*(const float4*)wp, *(const float4*)(wp + 4));
                    acc[i] = __builtin_amdgcn_mfma_f32_16x16x32_f16(Af, Yf[ks], acc[i], 0, 0, 0);
                }
            }
            __builtin_amdgcn_s_setprio(0);
            #pragma unroll
            for (int i = 0; i < 4; ++i) {
                int obase = ch * 64 + 16 * i + 4 * g;
                *(float4*)(out + (size_t)(p0 + li) * DDIM + obase) =
                    make_float4(acc[i][0], acc[i][1], acc[i][2], acc[i][3]);
            }
        }
    }

    // ---- commit loss: full-wave shuffle reduce + one atomic ----
    {
        float cp = commit_part;
        #pragma unroll
        for (int m = 1; m <= 32; m <<= 1) cp += __shfl_xor(cp, m);
        if (lane == 0)
            atomicAdd(out + (size_t)NPTS * DDIM + NPTS,
                      cp * (1.0f / ((float)NPTS * (float)DDIM)));
    }
}

// ---------------------------------------------------------------------------
extern "C" void kernel_launch(void* const* d_in, const int* in_sizes, int n_in,
                              void* d_out, int out_size, void* d_ws, size_t ws_size,
                              hipStream_t stream) {
    const float* x    = (const float*)d_in[0];
    const float* cb   = (const float*)d_in[1];
    const float* linw = (const float*)d_in[2];
    const float* linb = (const float*)d_in[3];
    float* out    = (float*)d_out;
    float* norms  = (float*)d_ws;                        // 3072 f
    float* ascore = norms + 4096;                        // 3072 f
    f16*   cb16   = (f16*)((char*)d_ws + 32768);         // 786432 B
    const size_t need = 32768 + (size_t)NVQ * KCODES * DDIM * 2;

    zero_commit_kernel<<<1, 1, 0, stream>>>(out + (size_t)NPTS * DDIM + NPTS);
    norms_kernel<<<NVQ * KCODES, 64, 0, stream>>>(cb, norms, ascore);

    if (ws_size >= need) {
        preconv_kernel<<<(NVQ * KCODES * DDIM) / (256 * 8), 256, 0, stream>>>(cb, cb16);
        rvq_kernel<true><<<NPTS / TM, BLOCKT, 0, stream>>>(x, cb, cb16, linw, linb,
                                                           norms, ascore, out);
    } else {
        rvq_kernel<false><<<NPTS / TM, BLOCKT, 0, stream>>>(x, cb, cb16, linw, linb,
                                                            norms, ascore, out);
    }
}

// Round 14
// 655.287 us; speedup vs baseline: 2.8720x; 2.8720x over previous
//
#include <hip/hip_runtime.h>
#include <float.h>

typedef _Float16 f16;
typedef f16 f16x8 __attribute__((ext_vector_type(8)));
typedef float f32x4 __attribute__((ext_vector_type(4)));
typedef unsigned int u32;

#define NPTS 262144
#define DDIM 128
#define NVQ 6
#define KCODES 512
#define TM 64
#define BLOCKT 256

#define GLD16(gp, lp)                                                          \
    __builtin_amdgcn_global_load_lds(                                          \
        (const __attribute__((address_space(1))) void*)(gp),                   \
        (__attribute__((address_space(3))) void*)(lp), 16, 0, 0)

__device__ __forceinline__ int swz(int row, int grp) {
    return row * DDIM + ((grp ^ (row & 7)) << 3);
}
__device__ __forceinline__ u32 umin32(u32 a, u32 b) { return a < b ? a : b; }
__device__ __forceinline__ u32 umax32(u32 a, u32 b) { return a > b ? a : b; }

__device__ __forceinline__ f16x8 cvt8(float4 a, float4 b) {
    f16x8 h;
    h[0] = (f16)a.x; h[1] = (f16)a.y; h[2] = (f16)a.z; h[3] = (f16)a.w;
    h[4] = (f16)b.x; h[5] = (f16)b.y; h[6] = (f16)b.z; h[7] = (f16)b.w;
    return h;
}

// ---------------------------------------------------------------------------
__global__ void zero_commit_kernel(float* p) { *p = 0.0f; }

__global__ void norms_kernel(const float* __restrict__ cb, float* __restrict__ norms,
                             float* __restrict__ ascore) {
    int row = blockIdx.x;
    int lane = threadIdx.x;
    const float* r = cb + (size_t)row * DDIM;
    float2 v = *(const float2*)(r + lane * 2);
    float s = v.x * v.x + v.y * v.y;
    #pragma unroll
    for (int m = 32; m >= 1; m >>= 1) s += __shfl_xor(s, m);
    if (lane == 0) { norms[row] = s; ascore[row] = 512.0f - 0.5f * s; }
}

__global__ void preconv_kernel(const float* __restrict__ cb, f16* __restrict__ cb16) {
    size_t base = ((size_t)blockIdx.x * 256 + threadIdx.x) * 8;
    float4 a = *(const float4*)(cb + base);
    float4 b = *(const float4*)(cb + base + 4);
    *(f16x8*)(cb16 + base) = cvt8(a, b);
}

// ---------------------------------------------------------------------------
// Residual VQ — r11 decomposition (best passing: 812us, absmax 5.421875) with
// the A-path rebuilt as wave-PRIVATE global_load_lds double-buffering:
//  - r13 proved A-delivery is the stall (4x A-traffic -> 2.4x slower;
//    r11 MfmaUtil 11% ~= per-chunk period 730cy vs 80cy MFMA).
//  - Each wave stages its next 16-code tile (4KB) into its own LDS dbuf via
//    4x global_load_lds width=16 (no VGPRs in flight -> also removes the A
//    in-flight registers behind r11's residual spill). No cross-wave sharing
//    -> NO new barriers; chunk loop stays per-wave independent.
//  - Counted s_waitcnt vmcnt(4): FIFO semantics guarantee everything older
//    than the newest 4 loads is done -> current chunk ready; any interleaved
//    scratch/VMEM can only over-wait, never under-wait -> race-free.
//  - Source pre-swizzled (grp ^ (row&7), both-sides rule) so ds_read_b128 of
//    A-fragments is ~conflict-free; A bytes and MFMA order BIT-IDENTICAL to
//    r11 -> selection unchanged. ascore served from LDS so the chunk loop's
//    only VMEM ops are the 4 gload_lds (clean vmcnt counting).
// FP ORDER FROZEN: ks=0,1,2,3 per acc[j]; ascore added after (r8/r9 lesson).
template<bool PRE>
__global__ __launch_bounds__(BLOCKT)
__attribute__((amdgpu_waves_per_eu(3, 3)))
void rvq_kernel(const float* __restrict__ x, const float* __restrict__ cb,
                const f16* __restrict__ cb16, const float* __restrict__ W,
                const float* __restrict__ bias, const float* __restrict__ norms,
                const float* __restrict__ ascore, float* __restrict__ out) {
    __shared__ f16   rh[TM * DDIM];     // 16 KB residual/y fp16, swizzled
    __shared__ f16   ebuf[4][2][2048];  // 32 KB wave-private A dbuf (4KB x 2 x wave)
    __shared__ float as_lds[KCODES];    // 2 KB ascore slice for current stage
    __shared__ uint2 cand[4][TM];       // 2 KB per-wave top2 keys per point

    const int tid  = threadIdx.x;
    const int wid  = tid >> 6;
    const int lane = tid & 63;
    const int g    = lane >> 4;      // k-group 0..3
    const int li   = lane & 15;      // row/col within 16-tile
    const int p_own = tid >> 2;      // owned point 0..63
    const int q     = tid & 3;       // owned d-quarter
    const int p0    = blockIdx.x * TM;

    // staging geometry (per wave): row = it*4 + (lane>>4), grp = lane&15
    const int srow = (lane >> 4);
    const int sgrp = lane & 15;

    // ---- x -> r (regs) and rh (fp16 LDS) ----
    float r[32];
    {
        const float* xs = x + (size_t)(p0 + p_own) * DDIM + q * 32;
        #pragma unroll
        for (int k = 0; k < 8; ++k) {
            float4 v = *(const float4*)(xs + 4 * k);
            r[4*k] = v.x; r[4*k+1] = v.y; r[4*k+2] = v.z; r[4*k+3] = v.w;
        }
    }
    #pragma unroll
    for (int k = 0; k < 4; ++k) {
        f16x8 h;
        #pragma unroll
        for (int m = 0; m < 8; ++m) h[m] = (f16)r[8*k+m];
        *(f16x8*)&rh[swz(p_own, q * 4 + k)] = h;
    }
    __syncthreads();

    float commit_part = 0.0f;

    #pragma unroll 1
    for (int s = 0; s < NVQ; ++s) {
        // ---- B fragments from rh (one b128 each), reused over all 512 codes ----
        f16x8 Bf[4][4];
        #pragma unroll
        for (int j = 0; j < 4; ++j)
            #pragma unroll
            for (int ks = 0; ks < 4; ++ks)
                Bf[j][ks] = *(const f16x8*)&rh[swz(16 * j + li, ks * 4 + g)];

        // ---- ascore slice -> LDS (keeps chunk-loop VMEM = gload_lds only) ----
        as_lds[tid]       = ascore[s * KCODES + tid];
        as_lds[tid + 256] = ascore[s * KCODES + tid + 256];
        __syncthreads();

        u32 k1[4], k2[4];
        #pragma unroll
        for (int j = 0; j < 4; ++j) { k1[j] = 0u; k2[j] = 0u; }

        if constexpr (PRE) {
            // wave's global base: code = s*512 + ch*64 + 16*wid + row
            const char* gsb = (const char*)cb16 +
                              ((size_t)s * KCODES + 16 * wid) * (DDIM * 2);
            char* lb0 = (char*)&ebuf[wid][0][0];
            char* lb1 = (char*)&ebuf[wid][1][0];

            // ---- prologue: stage chunk 0 ----
            #pragma unroll
            for (int it = 0; it < 4; ++it) {
                int row = it * 4 + srow;
                GLD16(gsb + row * 256 + ((sgrp ^ (row & 7)) << 4), lb0 + it * 1024);
            }

            #pragma unroll 2
            for (int ch = 0; ch < 8; ++ch) {
                char* cur = (ch & 1) ? lb1 : lb0;
                char* nxt = (ch & 1) ? lb0 : lb1;
                if (ch < 7) {
                    #pragma unroll
                    for (int it = 0; it < 4; ++it) {
                        int row = it * 4 + srow;
                        GLD16(gsb + (size_t)(ch + 1) * 16384 + row * 256 +
                                  ((sgrp ^ (row & 7)) << 4),
                              nxt + it * 1024);
                    }
                    asm volatile("s_waitcnt vmcnt(4)" ::: "memory");
                } else {
                    asm volatile("s_waitcnt vmcnt(0)" ::: "memory");
                }

                float4 as4 = *(const float4*)&as_lds[ch * 64 + 16 * wid + 4 * g];
                f32x4 acc[4];
                #pragma unroll
                for (int j = 0; j < 4; ++j) acc[j] = (f32x4)0.0f;

                __builtin_amdgcn_s_setprio(1);
                #pragma unroll
                for (int ks = 0; ks < 4; ++ks) {
                    f16x8 Af = *(const f16x8*)(cur + li * 256 +
                                               (((ks * 4 + g) ^ (li & 7)) << 4));
                    #pragma unroll
                    for (int j = 0; j < 4; ++j)
                        acc[j] = __builtin_amdgcn_mfma_f32_16x16x32_f16(Af, Bf[j][ks], acc[j], 0, 0, 0);
                }
                __builtin_amdgcn_s_setprio(0);

                const int invc = 511 - (ch * 64 + 16 * wid + 4 * g);
                #pragma unroll
                for (int j = 0; j < 4; ++j) {
                    #pragma unroll
                    for (int reg = 0; reg < 4; ++reg) {
                        float sc = acc[j][reg] +
                            ((reg == 0) ? as4.x : (reg == 1) ? as4.y : (reg == 2) ? as4.z : as4.w);
                        u32 key = (__float_as_uint(sc) & 0xFFFFFE00u) | (u32)(invc - reg);
                        u32 lo = umin32(k1[j], key);
                        k1[j] = umax32(k1[j], key);
                        k2[j] = umax32(k2[j], lo);
                    }
                }
            }
        } else {
            // fallback: r11 direct-global path (fp32 cvt)
            const float* Ab32 = cb + ((size_t)s * KCODES + 16 * wid + li) * DDIM + g * 8;
            #pragma unroll 2
            for (int ch = 0; ch < 8; ++ch) {
                float4 as4 = *(const float4*)&as_lds[ch * 64 + 16 * wid + 4 * g];
                f32x4 acc[4];
                #pragma unroll
                for (int j = 0; j < 4; ++j) acc[j] = (f32x4)0.0f;
                #pragma unroll
                for (int ks = 0; ks < 4; ++ks) {
                    const float* ap = Ab32 + (size_t)ch * 64 * DDIM + ks * 32;
                    f16x8 Af = cvt8(*(const float4*)ap, *(const float4*)(ap + 4));
                    #pragma unroll
                    for (int j = 0; j < 4; ++j)
                        acc[j] = __builtin_amdgcn_mfma_f32_16x16x32_f16(Af, Bf[j][ks], acc[j], 0, 0, 0);
                }
                const int invc = 511 - (ch * 64 + 16 * wid + 4 * g);
                #pragma unroll
                for (int j = 0; j < 4; ++j) {
                    #pragma unroll
                    for (int reg = 0; reg < 4; ++reg) {
                        float sc = acc[j][reg] +
                            ((reg == 0) ? as4.x : (reg == 1) ? as4.y : (reg == 2) ? as4.z : as4.w);
                        u32 key = (__float_as_uint(sc) & 0xFFFFFE00u) | (u32)(invc - reg);
                        u32 lo = umin32(k1[j], key);
                        k1[j] = umax32(k1[j], key);
                        k2[j] = umax32(k2[j], lo);
                    }
                }
            }
        }

        // ---- in-wave top-2 butterfly across k-groups (lanes xor 16, 32) ----
        #pragma unroll
        for (int m = 16; m <= 32; m <<= 1) {
            #pragma unroll
            for (int j = 0; j < 4; ++j) {
                u32 o1 = (u32)__shfl_xor((int)k1[j], m);
                u32 o2 = (u32)__shfl_xor((int)k2[j], m);
                u32 lo = umin32(k1[j], o1);
                k1[j] = umax32(k1[j], o1);
                k2[j] = umax32(umax32(k2[j], o2), lo);
            }
        }
        if (lane < 16) {
            #pragma unroll
            for (int j = 0; j < 4; ++j)
                cand[wid][16 * j + li] = make_uint2(k1[j], k2[j]);
        }
        __syncthreads();   // also: all waves done reading rh/as_lds this stage

        // ---- cross-wave merge, redundantly in every thread ----
        uint2 v0 = cand[0][p_own];
        u32 m1 = v0.x, m2 = v0.y;
        #pragma unroll
        for (int w = 1; w < 4; ++w) {
            uint2 vv = cand[w][p_own];
            u32 lo = umin32(m1, vv.x);
            m1 = umax32(m1, vv.x);
            m2 = umax32(umax32(m2, vv.y), lo);
        }
        int c1 = 511 - (int)(m1 & 0x1FFu);
        int c2 = 511 - (int)(m2 & 0x1FFu);

        // ---- exact fp32 rescue on top-2 (registers only) ----
        const float* E1 = cb + (size_t)(s * KCODES + c1) * DDIM + q * 32;
        const float* E2 = cb + (size_t)(s * KCODES + c2) * DDIM + q * 32;
        float dot1 = 0.0f, dot2 = 0.0f;
        #pragma unroll
        for (int k = 0; k < 8; ++k) {
            float4 a = *(const float4*)(E1 + 4 * k);
            dot1 += a.x * r[4*k] + a.y * r[4*k+1] + a.z * r[4*k+2] + a.w * r[4*k+3];
        }
        #pragma unroll
        for (int k = 0; k < 8; ++k) {
            float4 a = *(const float4*)(E2 + 4 * k);
            dot2 += a.x * r[4*k] + a.y * r[4*k+1] + a.z * r[4*k+2] + a.w * r[4*k+3];
        }
        dot1 += __shfl_xor(dot1, 1); dot1 += __shfl_xor(dot1, 2);
        dot2 += __shfl_xor(dot2, 1); dot2 += __shfl_xor(dot2, 2);
        float d1e = fmaf(-2.0f, dot1, norms[s * KCODES + c1]);
        float d2e = fmaf(-2.0f, dot2, norms[s * KCODES + c2]);
        int best = (d2e < d1e || (d2e == d1e && c2 < c1)) ? c2 : c1;

        if (s == 0 && q == 0)
            out[(size_t)NPTS * DDIM + p0 + p_own] = (float)best;

        // ---- exact residual update (regs) + rh rewrite for next stage ----
        {
            const float* Eb = cb + (size_t)(s * KCODES + best) * DDIM + q * 32;
            float cp = 0.0f;
            #pragma unroll
            for (int k = 0; k < 8; ++k) {
                float4 e = *(const float4*)(Eb + 4 * k);
                r[4*k]   -= e.x; r[4*k+1] -= e.y; r[4*k+2] -= e.z; r[4*k+3] -= e.w;
                cp += r[4*k]*r[4*k] + r[4*k+1]*r[4*k+1] + r[4*k+2]*r[4*k+2] + r[4*k+3]*r[4*k+3];
            }
            if (s == 0) commit_part = cp;
        }
        if (s < NVQ - 1) {
            #pragma unroll
            for (int k = 0; k < 4; ++k) {
                f16x8 h;
                #pragma unroll
                for (int m = 0; m < 8; ++m) h[m] = (f16)r[8*k+m];
                *(f16x8*)&rh[swz(p_own, q * 4 + k)] = h;
            }
        }
        __syncthreads();
    }

    // ---- y = x - r_final -> rh ----
    {
        const float* xs = x + (size_t)(p0 + p_own) * DDIM + q * 32;
        #pragma unroll
        for (int k = 0; k < 4; ++k) {
            float4 a = *(const float4*)(xs + 8 * k);
            float4 b = *(const float4*)(xs + 8 * k + 4);
            f16x8 h;
            h[0]=(f16)(a.x - r[8*k+0]); h[1]=(f16)(a.y - r[8*k+1]);
            h[2]=(f16)(a.z - r[8*k+2]); h[3]=(f16)(a.w - r[8*k+3]);
            h[4]=(f16)(b.x - r[8*k+4]); h[5]=(f16)(b.y - r[8*k+5]);
            h[6]=(f16)(b.z - r[8*k+6]); h[7]=(f16)(b.w - r[8*k+7]);
            *(f16x8*)&rh[swz(p_own, q * 4 + k)] = h;
        }
    }
    __syncthreads();

    // ---- final linear: out = y @ W^T + b (W rows streamed from global) ----
    {
        f16x8 Yf[4][4];
        #pragma unroll
        for (int j = 0; j < 4; ++j)
            #pragma unroll
            for (int ks = 0; ks < 4; ++ks)
                Yf[j][ks] = *(const f16x8*)&rh[swz(16 * j + li, ks * 4 + g)];

        #pragma unroll 1
        for (int ch = 0; ch < 2; ++ch) {
            float4 b4 = *(const float4*)(bias + ch * 64 + 16 * wid + 4 * g);
            f32x4 acc[4];
            #pragma unroll
            for (int j = 0; j < 4; ++j) {
                acc[j][0] = b4.x; acc[j][1] = b4.y; acc[j][2] = b4.z; acc[j][3] = b4.w;
            }
            __builtin_amdgcn_s_setprio(1);
            #pragma unroll
            for (int ks = 0; ks < 4; ++ks) {
                const float* wp = W + (size_t)(ch * 64 + 16 * wid + li) * DDIM + ks * 32 + g * 8;
                f16x8 Af = cvt8(*(const float4*)wp, *(const float4*)(wp + 4));
                #pragma unroll
                for (int j = 0; j < 4; ++j)
                    acc[j] = __builtin_amdgcn_mfma_f32_16x16x32_f16(Af, Yf[j][ks], acc[j], 0, 0, 0);
            }
            __builtin_amdgcn_s_setprio(0);
            int obase = ch * 64 + 16 * wid + 4 * g;
            #pragma unroll
            for (int j = 0; j < 4; ++j)
                *(float4*)(out + (size_t)(p0 + 16 * j + li) * DDIM + obase) =
                    make_float4(acc[j][0], acc[j][1], acc[j][2], acc[j][3]);
        }
    }

    // ---- commit loss: wave shuffle-reduce + block atomic ----
    {
        float cp = commit_part;
        #pragma unroll
        for (int m = 1; m <= 32; m <<= 1) cp += __shfl_xor(cp, m);
        __syncthreads();
        float* wsum = (float*)cand;
        if (lane == 0) wsum[wid] = cp;
        __syncthreads();
        if (tid == 0) {
            float t = (wsum[0] + wsum[1]) + (wsum[2] + wsum[3]);
            atomicAdd(out + (size_t)NPTS * DDIM + NPTS,
                      t * (1.0f / ((float)NPTS * (float)DDIM)));
        }
    }
}

// ---------------------------------------------------------------------------
extern "C" void kernel_launch(void* const* d_in, const int* in_sizes, int n_in,
                              void* d_out, int out_size, void* d_ws, size_t ws_size,
                              hipStream_t stream) {
    const float* x    = (const float*)d_in[0];
    const float* cb   = (const float*)d_in[1];
    const float* linw = (const float*)d_in[2];
    const float* linb = (const float*)d_in[3];
    float* out    = (float*)d_out;
    float* norms  = (float*)d_ws;                        // 3072 f
    float* ascore = norms + 4096;                        // 3072 f
    f16*   cb16   = (f16*)((char*)d_ws + 32768);         // 786432 B
    const size_t need = 32768 + (size_t)NVQ * KCODES * DDIM * 2;

    zero_commit_kernel<<<1, 1, 0, stream>>>(out + (size_t)NPTS * DDIM + NPTS);
    norms_kernel<<<NVQ * KCODES, 64, 0, stream>>>(cb, norms, ascore);

    if (ws_size >= need) {
        preconv_kernel<<<(NVQ * KCODES * DDIM) / (256 * 8), 256, 0, stream>>>(cb, cb16);
        rvq_kernel<true><<<NPTS / TM, BLOCKT, 0, stream>>>(x, cb, cb16, linw, linb,
                                                           norms, ascore, out);
    } else {
        rvq_kernel<false><<<NPTS / TM, BLOCKT, 0, stream>>>(x, cb, cb16, linw, linb,
                                                            norms, ascore, out);
    }
}

// Round 15
// 635.456 us; speedup vs baseline: 2.9617x; 1.0312x over previous
//
#include <hip/hip_runtime.h>
#include <float.h>

typedef _Float16 f16;
typedef f16 f16x8 __attribute__((ext_vector_type(8)));
typedef float f32x4 __attribute__((ext_vector_type(4)));
typedef unsigned int u32;

#define NPTS 262144
#define DDIM 128
#define NVQ 6
#define KCODES 512
#define TM 64
#define BLOCKT 256

#define GLD16(gp, lp)                                                          \
    __builtin_amdgcn_global_load_lds(                                          \
        (const __attribute__((address_space(1))) void*)(gp),                   \
        (__attribute__((address_space(3))) void*)(lp), 16, 0, 0)

__device__ __forceinline__ int swz(int row, int grp) {
    return row * DDIM + ((grp ^ (row & 7)) << 3);
}
__device__ __forceinline__ u32 umin32(u32 a, u32 b) { return a < b ? a : b; }
__device__ __forceinline__ u32 umax32(u32 a, u32 b) { return a > b ? a : b; }

__device__ __forceinline__ f16x8 cvt8(float4 a, float4 b) {
    f16x8 h;
    h[0] = (f16)a.x; h[1] = (f16)a.y; h[2] = (f16)a.z; h[3] = (f16)a.w;
    h[4] = (f16)b.x; h[5] = (f16)b.y; h[6] = (f16)b.z; h[7] = (f16)b.w;
    return h;
}

// ---------------------------------------------------------------------------
__global__ void zero_commit_kernel(float* p) { *p = 0.0f; }

__global__ void norms_kernel(const float* __restrict__ cb, float* __restrict__ norms,
                             float* __restrict__ ascore) {
    int row = blockIdx.x;
    int lane = threadIdx.x;
    const float* r = cb + (size_t)row * DDIM;
    float2 v = *(const float2*)(r + lane * 2);
    float s = v.x * v.x + v.y * v.y;
    #pragma unroll
    for (int m = 32; m >= 1; m >>= 1) s += __shfl_xor(s, m);
    if (lane == 0) { norms[row] = s; ascore[row] = 512.0f - 0.5f * s; }
}

__global__ void preconv_kernel(const float* __restrict__ cb, f16* __restrict__ cb16) {
    size_t base = ((size_t)blockIdx.x * 256 + threadIdx.x) * 8;
    float4 a = *(const float4*)(cb + base);
    float4 b = *(const float4*)(cb + base + 4);
    *(f16x8*)(cb16 + base) = cvt8(a, b);
}

// ---------------------------------------------------------------------------
// Residual VQ — r14 (PASSING, 710us rocprof, absmax 5.421875) with pure
// SCHEDULING deltas (no FP / byte changes -> selection bit-identical):
//  (1) 3 -> 2 barriers/stage: as_lds for stage s+1 is filled in the TAIL of
//      stage s (post-SYNC-B all waves finished reading it; SYNC-C publishes),
//      ascore prefetched to regs early in the tail (latency under rescue).
//  (2) cross-stage chunk-0 prefetch: s+1's first A-tile issued right after
//      s's last chunk -> staging latency hides under butterfly/merge/rescue.
//      vmcnt stays sound by FIFO: at s+1 ch0 we issue ch1's 4 loads then
//      vmcnt(4) -> all older (incl. prologue) complete. Rescue loads are
//      compiler-modeled, so their waits account for outstanding gload_lds.
//  Buffer parity is stage-invariant (8 chunks -> chunk0 always lb0).
// FP ORDER FROZEN: ks=0,1,2,3 per acc[j]; ascore added after (r8/r9 lesson).
template<bool PRE>
__global__ __launch_bounds__(BLOCKT)
__attribute__((amdgpu_waves_per_eu(3, 3)))
void rvq_kernel(const float* __restrict__ x, const float* __restrict__ cb,
                const f16* __restrict__ cb16, const float* __restrict__ W,
                const float* __restrict__ bias, const float* __restrict__ norms,
                const float* __restrict__ ascore, float* __restrict__ out) {
    __shared__ f16   rh[TM * DDIM];     // 16 KB residual/y fp16, swizzled
    __shared__ f16   ebuf[4][2][2048];  // 32 KB wave-private A dbuf
    __shared__ float as_lds[KCODES];    // 2 KB ascore slice (current stage)
    __shared__ uint2 cand[4][TM];       // 2 KB per-wave top2 keys per point

    const int tid  = threadIdx.x;
    const int wid  = tid >> 6;
    const int lane = tid & 63;
    const int g    = lane >> 4;      // k-group 0..3
    const int li   = lane & 15;      // row/col within 16-tile
    const int p_own = tid >> 2;      // owned point 0..63
    const int q     = tid & 3;       // owned d-quarter
    const int p0    = blockIdx.x * TM;

    const int srow = (lane >> 4);    // staging row group
    const int sgrp = lane & 15;      // staging 16B group

    // ---- x -> r (regs) and rh (fp16 LDS) ----
    float r[32];
    {
        const float* xs = x + (size_t)(p0 + p_own) * DDIM + q * 32;
        #pragma unroll
        for (int k = 0; k < 8; ++k) {
            float4 v = *(const float4*)(xs + 4 * k);
            r[4*k] = v.x; r[4*k+1] = v.y; r[4*k+2] = v.z; r[4*k+3] = v.w;
        }
    }
    #pragma unroll
    for (int k = 0; k < 4; ++k) {
        f16x8 h;
        #pragma unroll
        for (int m = 0; m < 8; ++m) h[m] = (f16)r[8*k+m];
        *(f16x8*)&rh[swz(p_own, q * 4 + k)] = h;
    }

    // ---- pre-loop: as_lds for s=0 + stage s=0 chunk-0 A-tile ----
    as_lds[tid]       = ascore[tid];
    as_lds[tid + 256] = ascore[tid + 256];
    if constexpr (PRE) {
        const char* gsb0 = (const char*)cb16 + ((size_t)16 * wid) * (DDIM * 2);
        char* lb0 = (char*)&ebuf[wid][0][0];
        #pragma unroll
        for (int it = 0; it < 4; ++it) {
            int row = it * 4 + srow;
            GLD16(gsb0 + row * 256 + ((sgrp ^ (row & 7)) << 4), lb0 + it * 1024);
        }
    }
    __syncthreads();

    float commit_part = 0.0f;

    #pragma unroll 1
    for (int s = 0; s < NVQ; ++s) {
        // ---- B fragments from rh (protected by previous stage's SYNC-C) ----
        f16x8 Bf[4][4];
        #pragma unroll
        for (int j = 0; j < 4; ++j)
            #pragma unroll
            for (int ks = 0; ks < 4; ++ks)
                Bf[j][ks] = *(const f16x8*)&rh[swz(16 * j + li, ks * 4 + g)];

        u32 k1[4], k2[4];
        #pragma unroll
        for (int j = 0; j < 4; ++j) { k1[j] = 0u; k2[j] = 0u; }

        if constexpr (PRE) {
            const char* gsb = (const char*)cb16 +
                              ((size_t)s * KCODES + 16 * wid) * (DDIM * 2);
            char* lb0 = (char*)&ebuf[wid][0][0];
            char* lb1 = (char*)&ebuf[wid][1][0];

            #pragma unroll 2
            for (int ch = 0; ch < 8; ++ch) {
                char* cur = (ch & 1) ? lb1 : lb0;
                char* nxt = (ch & 1) ? lb0 : lb1;
                if (ch < 7) {
                    #pragma unroll
                    for (int it = 0; it < 4; ++it) {
                        int row = it * 4 + srow;
                        GLD16(gsb + (size_t)(ch + 1) * 16384 + row * 256 +
                                  ((sgrp ^ (row & 7)) << 4),
                              nxt + it * 1024);
                    }
                    asm volatile("s_waitcnt vmcnt(4)" ::: "memory");
                } else {
                    asm volatile("s_waitcnt vmcnt(0)" ::: "memory");
                }

                float4 as4 = *(const float4*)&as_lds[ch * 64 + 16 * wid + 4 * g];
                f32x4 acc[4];
                #pragma unroll
                for (int j = 0; j < 4; ++j) acc[j] = (f32x4)0.0f;

                __builtin_amdgcn_s_setprio(1);
                #pragma unroll
                for (int ks = 0; ks < 4; ++ks) {
                    f16x8 Af = *(const f16x8*)(cur + li * 256 +
                                               (((ks * 4 + g) ^ (li & 7)) << 4));
                    #pragma unroll
                    for (int j = 0; j < 4; ++j)
                        acc[j] = __builtin_amdgcn_mfma_f32_16x16x32_f16(Af, Bf[j][ks], acc[j], 0, 0, 0);
                }
                __builtin_amdgcn_s_setprio(0);

                const int invc = 511 - (ch * 64 + 16 * wid + 4 * g);
                #pragma unroll
                for (int j = 0; j < 4; ++j) {
                    #pragma unroll
                    for (int reg = 0; reg < 4; ++reg) {
                        float sc = acc[j][reg] +
                            ((reg == 0) ? as4.x : (reg == 1) ? as4.y : (reg == 2) ? as4.z : as4.w);
                        u32 key = (__float_as_uint(sc) & 0xFFFFFE00u) | (u32)(invc - reg);
                        u32 lo = umin32(k1[j], key);
                        k1[j] = umax32(k1[j], key);
                        k2[j] = umax32(k2[j], lo);
                    }
                }
            }

            // ---- cross-stage prologue: issue s+1 chunk 0 into lb0 now; its
            //      latency hides under butterfly/merge/rescue/barriers ----
            if (s < NVQ - 1) {
                const char* gsbn = gsb + (size_t)KCODES * DDIM * 2;
                #pragma unroll
                for (int it = 0; it < 4; ++it) {
                    int row = it * 4 + srow;
                    GLD16(gsbn + row * 256 + ((sgrp ^ (row & 7)) << 4),
                          lb0 + it * 1024);
                }
            }
        } else {
            const float* Ab32 = cb + ((size_t)s * KCODES + 16 * wid + li) * DDIM + g * 8;
            #pragma unroll 2
            for (int ch = 0; ch < 8; ++ch) {
                float4 as4 = *(const float4*)&as_lds[ch * 64 + 16 * wid + 4 * g];
                f32x4 acc[4];
                #pragma unroll
                for (int j = 0; j < 4; ++j) acc[j] = (f32x4)0.0f;
                #pragma unroll
                for (int ks = 0; ks < 4; ++ks) {
                    const float* ap = Ab32 + (size_t)ch * 64 * DDIM + ks * 32;
                    f16x8 Af = cvt8(*(const float4*)ap, *(const float4*)(ap + 4));
                    #pragma unroll
                    for (int j = 0; j < 4; ++j)
                        acc[j] = __builtin_amdgcn_mfma_f32_16x16x32_f16(Af, Bf[j][ks], acc[j], 0, 0, 0);
                }
                const int invc = 511 - (ch * 64 + 16 * wid + 4 * g);
                #pragma unroll
                for (int j = 0; j < 4; ++j) {
                    #pragma unroll
                    for (int reg = 0; reg < 4; ++reg) {
                        float sc = acc[j][reg] +
                            ((reg == 0) ? as4.x : (reg == 1) ? as4.y : (reg == 2) ? as4.z : as4.w);
                        u32 key = (__float_as_uint(sc) & 0xFFFFFE00u) | (u32)(invc - reg);
                        u32 lo = umin32(k1[j], key);
                        k1[j] = umax32(k1[j], key);
                        k2[j] = umax32(k2[j], lo);
                    }
                }
            }
        }

        // ---- in-wave top-2 butterfly across k-groups (lanes xor 16, 32) ----
        #pragma unroll
        for (int m = 16; m <= 32; m <<= 1) {
            #pragma unroll
            for (int j = 0; j < 4; ++j) {
                u32 o1 = (u32)__shfl_xor((int)k1[j], m);
                u32 o2 = (u32)__shfl_xor((int)k2[j], m);
                u32 lo = umin32(k1[j], o1);
                k1[j] = umax32(k1[j], o1);
                k2[j] = umax32(umax32(k2[j], o2), lo);
            }
        }
        if (lane < 16) {
            #pragma unroll
            for (int j = 0; j < 4; ++j)
                cand[wid][16 * j + li] = make_uint2(k1[j], k2[j]);
        }
        __syncthreads();   // SYNC-B: cand ready; all waves past chunk loop

        // ---- tail: ascore prefetch for s+1 (latency hides under rescue) ----
        float as_n0 = 0.0f, as_n1 = 0.0f;
        if (s < NVQ - 1) {
            as_n0 = ascore[(s + 1) * KCODES + tid];
            as_n1 = ascore[(s + 1) * KCODES + tid + 256];
        }

        // ---- cross-wave merge, redundantly in every thread ----
        uint2 v0 = cand[0][p_own];
        u32 m1 = v0.x, m2 = v0.y;
        #pragma unroll
        for (int w = 1; w < 4; ++w) {
            uint2 vv = cand[w][p_own];
            u32 lo = umin32(m1, vv.x);
            m1 = umax32(m1, vv.x);
            m2 = umax32(umax32(m2, vv.y), lo);
        }
        int c1 = 511 - (int)(m1 & 0x1FFu);
        int c2 = 511 - (int)(m2 & 0x1FFu);

        // ---- exact fp32 rescue on top-2 (registers only) ----
        const float* E1 = cb + (size_t)(s * KCODES + c1) * DDIM + q * 32;
        const float* E2 = cb + (size_t)(s * KCODES + c2) * DDIM + q * 32;
        float dot1 = 0.0f, dot2 = 0.0f;
        #pragma unroll
        for (int k = 0; k < 8; ++k) {
            float4 a = *(const float4*)(E1 + 4 * k);
            dot1 += a.x * r[4*k] + a.y * r[4*k+1] + a.z * r[4*k+2] + a.w * r[4*k+3];
        }
        #pragma unroll
        for (int k = 0; k < 8; ++k) {
            float4 a = *(const float4*)(E2 + 4 * k);
            dot2 += a.x * r[4*k] + a.y * r[4*k+1] + a.z * r[4*k+2] + a.w * r[4*k+3];
        }
        dot1 += __shfl_xor(dot1, 1); dot1 += __shfl_xor(dot1, 2);
        dot2 += __shfl_xor(dot2, 1); dot2 += __shfl_xor(dot2, 2);
        float d1e = fmaf(-2.0f, dot1, norms[s * KCODES + c1]);
        float d2e = fmaf(-2.0f, dot2, norms[s * KCODES + c2]);
        int best = (d2e < d1e || (d2e == d1e && c2 < c1)) ? c2 : c1;

        if (s == 0 && q == 0)
            out[(size_t)NPTS * DDIM + p0 + p_own] = (float)best;

        // ---- exact residual update (regs) + rh rewrite for next stage ----
        {
            const float* Eb = cb + (size_t)(s * KCODES + best) * DDIM + q * 32;
            float cp = 0.0f;
            #pragma unroll
            for (int k = 0; k < 8; ++k) {
                float4 e = *(const float4*)(Eb + 4 * k);
                r[4*k]   -= e.x; r[4*k+1] -= e.y; r[4*k+2] -= e.z; r[4*k+3] -= e.w;
                cp += r[4*k]*r[4*k] + r[4*k+1]*r[4*k+1] + r[4*k+2]*r[4*k+2] + r[4*k+3]*r[4*k+3];
            }
            if (s == 0) commit_part = cp;
        }
        if (s < NVQ - 1) {
            #pragma unroll
            for (int k = 0; k < 4; ++k) {
                f16x8 h;
                #pragma unroll
                for (int m = 0; m < 8; ++m) h[m] = (f16)r[8*k+m];
                *(f16x8*)&rh[swz(p_own, q * 4 + k)] = h;
            }
            // as_lds refill for s+1 (safe: all reads finished before SYNC-B)
            as_lds[tid]       = as_n0;
            as_lds[tid + 256] = as_n1;
        }
        __syncthreads();   // SYNC-C: rh + as_lds published for stage s+1
    }

    // ---- y = x - r_final -> rh ----
    {
        const float* xs = x + (size_t)(p0 + p_own) * DDIM + q * 32;
        #pragma unroll
        for (int k = 0; k < 4; ++k) {
            float4 a = *(const float4*)(xs + 8 * k);
            float4 b = *(const float4*)(xs + 8 * k + 4);
            f16x8 h;
            h[0]=(f16)(a.x - r[8*k+0]); h[1]=(f16)(a.y - r[8*k+1]);
            h[2]=(f16)(a.z - r[8*k+2]); h[3]=(f16)(a.w - r[8*k+3]);
            h[4]=(f16)(b.x - r[8*k+4]); h[5]=(f16)(b.y - r[8*k+5]);
            h[6]=(f16)(b.z - r[8*k+6]); h[7]=(f16)(b.w - r[8*k+7]);
            *(f16x8*)&rh[swz(p_own, q * 4 + k)] = h;
        }
    }
    __syncthreads();

    // ---- final linear: out = y @ W^T + b (W rows streamed from global) ----
    {
        f16x8 Yf[4][4];
        #pragma unroll
        for (int j = 0; j < 4; ++j)
            #pragma unroll
            for (int ks = 0; ks < 4; ++ks)
                Yf[j][ks] = *(const f16x8*)&rh[swz(16 * j + li, ks * 4 + g)];

        #pragma unroll 1
        for (int ch = 0; ch < 2; ++ch) {
            float4 b4 = *(const float4*)(bias + ch * 64 + 16 * wid + 4 * g);
            f32x4 acc[4];
            #pragma unroll
            for (int j = 0; j < 4; ++j) {
                acc[j][0] = b4.x; acc[j][1] = b4.y; acc[j][2] = b4.z; acc[j][3] = b4.w;
            }
            __builtin_amdgcn_s_setprio(1);
            #pragma unroll
            for (int ks = 0; ks < 4; ++ks) {
                const float* wp = W + (size_t)(ch * 64 + 16 * wid + li) * DDIM + ks * 32 + g * 8;
                f16x8 Af = cvt8(*(const float4*)wp, *(const float4*)(wp + 4));
                #pragma unroll
                for (int j = 0; j < 4; ++j)
                    acc[j] = __builtin_amdgcn_mfma_f32_16x16x32_f16(Af, Yf[j][ks], acc[j], 0, 0, 0);
            }
            __builtin_amdgcn_s_setprio(0);
            int obase = ch * 64 + 16 * wid + 4 * g;
            #pragma unroll
            for (int j = 0; j < 4; ++j)
                *(float4*)(out + (size_t)(p0 + 16 * j + li) * DDIM + obase) =
                    make_float4(acc[j][0], acc[j][1], acc[j][2], acc[j][3]);
        }
    }

    // ---- commit loss: wave shuffle-reduce + block atomic ----
    {
        float cp = commit_part;
        #pragma unroll
        for (int m = 1; m <= 32; m <<= 1) cp += __shfl_xor(cp, m);
        __syncthreads();
        float* wsum = (float*)cand;
        if (lane == 0) wsum[wid] = cp;
        __syncthreads();
        if (tid == 0) {
            float t = (wsum[0] + wsum[1]) + (wsum[2] + wsum[3]);
            atomicAdd(out + (size_t)NPTS * DDIM + NPTS,
                      t * (1.0f / ((float)NPTS * (float)DDIM)));
        }
    }
}

// ---------------------------------------------------------------------------
extern "C" void kernel_launch(void* const* d_in, const int* in_sizes, int n_in,
                              void* d_out, int out_size, void* d_ws, size_t ws_size,
                              hipStream_t stream) {
    const float* x    = (const float*)d_in[0];
    const float* cb   = (const float*)d_in[1];
    const float* linw = (const float*)d_in[2];
    const float* linb = (const float*)d_in[3];
    float* out    = (float*)d_out;
    float* norms  = (float*)d_ws;                        // 3072 f
    float* ascore = norms + 4096;                        // 3072 f
    f16*   cb16   = (f16*)((char*)d_ws + 32768);         // 786432 B
    const size_t need = 32768 + (size_t)NVQ * KCODES * DDIM * 2;

    zero_commit_kernel<<<1, 1, 0, stream>>>(out + (size_t)NPTS * DDIM + NPTS);
    norms_kernel<<<NVQ * KCODES, 64, 0, stream>>>(cb, norms, ascore);

    if (ws_size >= need) {
        preconv_kernel<<<(NVQ * KCODES * DDIM) / (256 * 8), 256, 0, stream>>>(cb, cb16);
        rvq_kernel<true><<<NPTS / TM, BLOCKT, 0, stream>>>(x, cb, cb16, linw, linb,
                                                           norms, ascore, out);
    } else {
        rvq_kernel<false><<<NPTS / TM, BLOCKT, 0, stream>>>(x, cb, cb16, linw, linb,
                                                            norms, ascore, out);
    }
}

// Round 16
// 624.489 us; speedup vs baseline: 3.0137x; 1.0176x over previous
//
#include <hip/hip_runtime.h>
#include <float.h>

typedef _Float16 f16;
typedef f16 f16x8 __attribute__((ext_vector_type(8)));
typedef float f32x4 __attribute__((ext_vector_type(4)));
typedef unsigned int u32;

#define NPTS 262144
#define DDIM 128
#define NVQ 6
#define KCODES 512
#define TM 64
#define BLOCKT 256

#define GLD16(gp, lp)                                                          \
    __builtin_amdgcn_global_load_lds(                                          \
        (const __attribute__((address_space(1))) void*)(gp),                   \
        (__attribute__((address_space(3))) void*)(lp), 16, 0, 0)

__device__ __forceinline__ int swz(int row, int grp) {
    return row * DDIM + ((grp ^ (row & 7)) << 3);
}
__device__ __forceinline__ u32 umin32(u32 a, u32 b) { return a < b ? a : b; }
__device__ __forceinline__ u32 umax32(u32 a, u32 b) { return a > b ? a : b; }

__device__ __forceinline__ f16x8 cvt8(float4 a, float4 b) {
    f16x8 h;
    h[0] = (f16)a.x; h[1] = (f16)a.y; h[2] = (f16)a.z; h[3] = (f16)a.w;
    h[4] = (f16)b.x; h[5] = (f16)b.y; h[6] = (f16)b.z; h[7] = (f16)b.w;
    return h;
}

// ---------------------------------------------------------------------------
__global__ void zero_commit_kernel(float* p) { *p = 0.0f; }

__global__ void norms_kernel(const float* __restrict__ cb, float* __restrict__ norms,
                             float* __restrict__ ascore) {
    int row = blockIdx.x;
    int lane = threadIdx.x;
    const float* r = cb + (size_t)row * DDIM;
    float2 v = *(const float2*)(r + lane * 2);
    float s = v.x * v.x + v.y * v.y;
    #pragma unroll
    for (int m = 32; m >= 1; m >>= 1) s += __shfl_xor(s, m);
    if (lane == 0) { norms[row] = s; ascore[row] = 512.0f - 0.5f * s; }
}

__global__ void preconv_kernel(const float* __restrict__ cb, f16* __restrict__ cb16) {
    size_t base = ((size_t)blockIdx.x * 256 + threadIdx.x) * 8;
    float4 a = *(const float4*)(cb + base);
    float4 b = *(const float4*)(cb + base + 4);
    *(f16x8*)(cb16 + base) = cvt8(a, b);
}

// ---------------------------------------------------------------------------
// Residual VQ — r15 body (PASSING, absmax 5.421875) + ascore FOLDED INTO the
// MFMA C-init (r4 precedent: init-first ordering passed with the identical
// absmax as add-last r5/r6 -> this transformation pair preserves selection).
// Epilogue per candidate: key-pack + 3 min/max (the fadd and as4-select are
// gone). C/D layout row=code -> init vector = as4 (same for all j).
// Other structure identical to r15:
//  - wave-private gload_lds A double-buffer, counted vmcnt(4)
//  - 2 barriers/stage; as_lds refilled in stage tail; cross-stage chunk-0
//    prefetch into lb0 (buffer parity stage-invariant).
// ks = 0,1,2,3 chain per acc[j] UNCHANGED (r8/r9: product-order reorder
// flips near-ties — never touch).
template<bool PRE>
__global__ __launch_bounds__(BLOCKT)
__attribute__((amdgpu_waves_per_eu(3, 3)))
void rvq_kernel(const float* __restrict__ x, const float* __restrict__ cb,
                const f16* __restrict__ cb16, const float* __restrict__ W,
                const float* __restrict__ bias, const float* __restrict__ norms,
                const float* __restrict__ ascore, float* __restrict__ out) {
    __shared__ f16   rh[TM * DDIM];     // 16 KB residual/y fp16, swizzled
    __shared__ f16   ebuf[4][2][2048];  // 32 KB wave-private A dbuf
    __shared__ float as_lds[KCODES];    // 2 KB ascore slice (current stage)
    __shared__ uint2 cand[4][TM];       // 2 KB per-wave top2 keys per point

    const int tid  = threadIdx.x;
    const int wid  = tid >> 6;
    const int lane = tid & 63;
    const int g    = lane >> 4;      // k-group 0..3
    const int li   = lane & 15;      // row/col within 16-tile
    const int p_own = tid >> 2;      // owned point 0..63
    const int q     = tid & 3;       // owned d-quarter
    const int p0    = blockIdx.x * TM;

    const int srow = (lane >> 4);    // staging row group
    const int sgrp = lane & 15;      // staging 16B group

    // ---- x -> r (regs) and rh (fp16 LDS) ----
    float r[32];
    {
        const float* xs = x + (size_t)(p0 + p_own) * DDIM + q * 32;
        #pragma unroll
        for (int k = 0; k < 8; ++k) {
            float4 v = *(const float4*)(xs + 4 * k);
            r[4*k] = v.x; r[4*k+1] = v.y; r[4*k+2] = v.z; r[4*k+3] = v.w;
        }
    }
    #pragma unroll
    for (int k = 0; k < 4; ++k) {
        f16x8 h;
        #pragma unroll
        for (int m = 0; m < 8; ++m) h[m] = (f16)r[8*k+m];
        *(f16x8*)&rh[swz(p_own, q * 4 + k)] = h;
    }

    // ---- pre-loop: as_lds for s=0 + stage s=0 chunk-0 A-tile ----
    as_lds[tid]       = ascore[tid];
    as_lds[tid + 256] = ascore[tid + 256];
    if constexpr (PRE) {
        const char* gsb0 = (const char*)cb16 + ((size_t)16 * wid) * (DDIM * 2);
        char* lb0 = (char*)&ebuf[wid][0][0];
        #pragma unroll
        for (int it = 0; it < 4; ++it) {
            int row = it * 4 + srow;
            GLD16(gsb0 + row * 256 + ((sgrp ^ (row & 7)) << 4), lb0 + it * 1024);
        }
    }
    __syncthreads();

    float commit_part = 0.0f;

    #pragma unroll 1
    for (int s = 0; s < NVQ; ++s) {
        // ---- B fragments from rh (protected by previous stage's SYNC-C) ----
        f16x8 Bf[4][4];
        #pragma unroll
        for (int j = 0; j < 4; ++j)
            #pragma unroll
            for (int ks = 0; ks < 4; ++ks)
                Bf[j][ks] = *(const f16x8*)&rh[swz(16 * j + li, ks * 4 + g)];

        u32 k1[4], k2[4];
        #pragma unroll
        for (int j = 0; j < 4; ++j) { k1[j] = 0u; k2[j] = 0u; }

        if constexpr (PRE) {
            const char* gsb = (const char*)cb16 +
                              ((size_t)s * KCODES + 16 * wid) * (DDIM * 2);
            char* lb0 = (char*)&ebuf[wid][0][0];
            char* lb1 = (char*)&ebuf[wid][1][0];

            #pragma unroll 2
            for (int ch = 0; ch < 8; ++ch) {
                char* cur = (ch & 1) ? lb1 : lb0;
                char* nxt = (ch & 1) ? lb0 : lb1;
                // init vector (LDS, hidden under staging issue): acc row=code
                float4 as4 = *(const float4*)&as_lds[ch * 64 + 16 * wid + 4 * g];
                if (ch < 7) {
                    #pragma unroll
                    for (int it = 0; it < 4; ++it) {
                        int row = it * 4 + srow;
                        GLD16(gsb + (size_t)(ch + 1) * 16384 + row * 256 +
                                  ((sgrp ^ (row & 7)) << 4),
                              nxt + it * 1024);
                    }
                    asm volatile("s_waitcnt vmcnt(4)" ::: "memory");
                } else {
                    asm volatile("s_waitcnt vmcnt(0)" ::: "memory");
                }

                f32x4 ainit;
                ainit[0] = as4.x; ainit[1] = as4.y; ainit[2] = as4.z; ainit[3] = as4.w;
                f32x4 acc[4];
                #pragma unroll
                for (int j = 0; j < 4; ++j) acc[j] = ainit;

                __builtin_amdgcn_s_setprio(1);
                #pragma unroll
                for (int ks = 0; ks < 4; ++ks) {
                    f16x8 Af = *(const f16x8*)(cur + li * 256 +
                                               (((ks * 4 + g) ^ (li & 7)) << 4));
                    #pragma unroll
                    for (int j = 0; j < 4; ++j)
                        acc[j] = __builtin_amdgcn_mfma_f32_16x16x32_f16(Af, Bf[j][ks], acc[j], 0, 0, 0);
                }
                __builtin_amdgcn_s_setprio(0);

                const int invc = 511 - (ch * 64 + 16 * wid + 4 * g);
                #pragma unroll
                for (int j = 0; j < 4; ++j) {
                    #pragma unroll
                    for (int reg = 0; reg < 4; ++reg) {
                        u32 key = (__float_as_uint(acc[j][reg]) & 0xFFFFFE00u) |
                                  (u32)(invc - reg);
                        u32 lo = umin32(k1[j], key);
                        k1[j] = umax32(k1[j], key);
                        k2[j] = umax32(k2[j], lo);
                    }
                }
            }

            // ---- cross-stage prologue: issue s+1 chunk 0 into lb0 now ----
            if (s < NVQ - 1) {
                const char* gsbn = gsb + (size_t)KCODES * DDIM * 2;
                #pragma unroll
                for (int it = 0; it < 4; ++it) {
                    int row = it * 4 + srow;
                    GLD16(gsbn + row * 256 + ((sgrp ^ (row & 7)) << 4),
                          lb0 + it * 1024);
                }
            }
        } else {
            const float* Ab32 = cb + ((size_t)s * KCODES + 16 * wid + li) * DDIM + g * 8;
            #pragma unroll 2
            for (int ch = 0; ch < 8; ++ch) {
                float4 as4 = *(const float4*)&as_lds[ch * 64 + 16 * wid + 4 * g];
                f32x4 ainit;
                ainit[0] = as4.x; ainit[1] = as4.y; ainit[2] = as4.z; ainit[3] = as4.w;
                f32x4 acc[4];
                #pragma unroll
                for (int j = 0; j < 4; ++j) acc[j] = ainit;
                #pragma unroll
                for (int ks = 0; ks < 4; ++ks) {
                    const float* ap = Ab32 + (size_t)ch * 64 * DDIM + ks * 32;
                    f16x8 Af = cvt8(*(const float4*)ap, *(const float4*)(ap + 4));
                    #pragma unroll
                    for (int j = 0; j < 4; ++j)
                        acc[j] = __builtin_amdgcn_mfma_f32_16x16x32_f16(Af, Bf[j][ks], acc[j], 0, 0, 0);
                }
                const int invc = 511 - (ch * 64 + 16 * wid + 4 * g);
                #pragma unroll
                for (int j = 0; j < 4; ++j) {
                    #pragma unroll
                    for (int reg = 0; reg < 4; ++reg) {
                        u32 key = (__float_as_uint(acc[j][reg]) & 0xFFFFFE00u) |
                                  (u32)(invc - reg);
                        u32 lo = umin32(k1[j], key);
                        k1[j] = umax32(k1[j], key);
                        k2[j] = umax32(k2[j], lo);
                    }
                }
            }
        }

        // ---- in-wave top-2 butterfly across k-groups (lanes xor 16, 32) ----
        #pragma unroll
        for (int m = 16; m <= 32; m <<= 1) {
            #pragma unroll
            for (int j = 0; j < 4; ++j) {
                u32 o1 = (u32)__shfl_xor((int)k1[j], m);
                u32 o2 = (u32)__shfl_xor((int)k2[j], m);
                u32 lo = umin32(k1[j], o1);
                k1[j] = umax32(k1[j], o1);
                k2[j] = umax32(umax32(k2[j], o2), lo);
            }
        }
        if (lane < 16) {
            #pragma unroll
            for (int j = 0; j < 4; ++j)
                cand[wid][16 * j + li] = make_uint2(k1[j], k2[j]);
        }
        __syncthreads();   // SYNC-B: cand ready; all waves past chunk loop

        // ---- tail: ascore prefetch for s+1 (latency hides under rescue) ----
        float as_n0 = 0.0f, as_n1 = 0.0f;
        if (s < NVQ - 1) {
            as_n0 = ascore[(s + 1) * KCODES + tid];
            as_n1 = ascore[(s + 1) * KCODES + tid + 256];
        }

        // ---- cross-wave merge, redundantly in every thread ----
        uint2 v0 = cand[0][p_own];
        u32 m1 = v0.x, m2 = v0.y;
        #pragma unroll
        for (int w = 1; w < 4; ++w) {
            uint2 vv = cand[w][p_own];
            u32 lo = umin32(m1, vv.x);
            m1 = umax32(m1, vv.x);
            m2 = umax32(umax32(m2, vv.y), lo);
        }
        int c1 = 511 - (int)(m1 & 0x1FFu);
        int c2 = 511 - (int)(m2 & 0x1FFu);

        // ---- exact fp32 rescue on top-2 (registers only) ----
        const float* E1 = cb + (size_t)(s * KCODES + c1) * DDIM + q * 32;
        const float* E2 = cb + (size_t)(s * KCODES + c2) * DDIM + q * 32;
        float dot1 = 0.0f, dot2 = 0.0f;
        #pragma unroll
        for (int k = 0; k < 8; ++k) {
            float4 a = *(const float4*)(E1 + 4 * k);
            dot1 += a.x * r[4*k] + a.y * r[4*k+1] + a.z * r[4*k+2] + a.w * r[4*k+3];
        }
        #pragma unroll
        for (int k = 0; k < 8; ++k) {
            float4 a = *(const float4*)(E2 + 4 * k);
            dot2 += a.x * r[4*k] + a.y * r[4*k+1] + a.z * r[4*k+2] + a.w * r[4*k+3];
        }
        dot1 += __shfl_xor(dot1, 1); dot1 += __shfl_xor(dot1, 2);
        dot2 += __shfl_xor(dot2, 1); dot2 += __shfl_xor(dot2, 2);
        float d1e = fmaf(-2.0f, dot1, norms[s * KCODES + c1]);
        float d2e = fmaf(-2.0f, dot2, norms[s * KCODES + c2]);
        int best = (d2e < d1e || (d2e == d1e && c2 < c1)) ? c2 : c1;

        if (s == 0 && q == 0)
            out[(size_t)NPTS * DDIM + p0 + p_own] = (float)best;

        // ---- exact residual update (regs) + rh rewrite for next stage ----
        {
            const float* Eb = cb + (size_t)(s * KCODES + best) * DDIM + q * 32;
            float cp = 0.0f;
            #pragma unroll
            for (int k = 0; k < 8; ++k) {
                float4 e = *(const float4*)(Eb + 4 * k);
                r[4*k]   -= e.x; r[4*k+1] -= e.y; r[4*k+2] -= e.z; r[4*k+3] -= e.w;
                cp += r[4*k]*r[4*k] + r[4*k+1]*r[4*k+1] + r[4*k+2]*r[4*k+2] + r[4*k+3]*r[4*k+3];
            }
            if (s == 0) commit_part = cp;
        }
        if (s < NVQ - 1) {
            #pragma unroll
            for (int k = 0; k < 4; ++k) {
                f16x8 h;
                #pragma unroll
                for (int m = 0; m < 8; ++m) h[m] = (f16)r[8*k+m];
                *(f16x8*)&rh[swz(p_own, q * 4 + k)] = h;
            }
            // as_lds refill for s+1 (safe: all reads finished before SYNC-B)
            as_lds[tid]       = as_n0;
            as_lds[tid + 256] = as_n1;
        }
        __syncthreads();   // SYNC-C: rh + as_lds published for stage s+1
    }

    // ---- y = x - r_final -> rh ----
    {
        const float* xs = x + (size_t)(p0 + p_own) * DDIM + q * 32;
        #pragma unroll
        for (int k = 0; k < 4; ++k) {
            float4 a = *(const float4*)(xs + 8 * k);
            float4 b = *(const float4*)(xs + 8 * k + 4);
            f16x8 h;
            h[0]=(f16)(a.x - r[8*k+0]); h[1]=(f16)(a.y - r[8*k+1]);
            h[2]=(f16)(a.z - r[8*k+2]); h[3]=(f16)(a.w - r[8*k+3]);
            h[4]=(f16)(b.x - r[8*k+4]); h[5]=(f16)(b.y - r[8*k+5]);
            h[6]=(f16)(b.z - r[8*k+6]); h[7]=(f16)(b.w - r[8*k+7]);
            *(f16x8*)&rh[swz(p_own, q * 4 + k)] = h;
        }
    }
    __syncthreads();

    // ---- final linear: out = y @ W^T + b (W rows streamed from global) ----
    {
        f16x8 Yf[4][4];
        #pragma unroll
        for (int j = 0; j < 4; ++j)
            #pragma unroll
            for (int ks = 0; ks < 4; ++ks)
                Yf[j][ks] = *(const f16x8*)&rh[swz(16 * j + li, ks * 4 + g)];

        #pragma unroll 1
        for (int ch = 0; ch < 2; ++ch) {
            float4 b4 = *(const float4*)(bias + ch * 64 + 16 * wid + 4 * g);
            f32x4 acc[4];
            #pragma unroll
            for (int j = 0; j < 4; ++j) {
                acc[j][0] = b4.x; acc[j][1] = b4.y; acc[j][2] = b4.z; acc[j][3] = b4.w;
            }
            __builtin_amdgcn_s_setprio(1);
            #pragma unroll
            for (int ks = 0; ks < 4; ++ks) {
                const float* wp = W + (size_t)(ch * 64 + 16 * wid + li) * DDIM + ks * 32 + g * 8;
                f16x8 Af = cvt8(*(const float4*)wp, *(const float4*)(wp + 4));
                #pragma unroll
                for (int j = 0; j < 4; ++j)
                    acc[j] = __builtin_amdgcn_mfma_f32_16x16x32_f16(Af, Yf[j][ks], acc[j], 0, 0, 0);
            }
            __builtin_amdgcn_s_setprio(0);
            int obase = ch * 64 + 16 * wid + 4 * g;
            #pragma unroll
            for (int j = 0; j < 4; ++j)
                *(float4*)(out + (size_t)(p0 + 16 * j + li) * DDIM + obase) =
                    make_float4(acc[j][0], acc[j][1], acc[j][2], acc[j][3]);
        }
    }

    // ---- commit loss: wave shuffle-reduce + block atomic ----
    {
        float cp = commit_part;
        #pragma unroll
        for (int m = 1; m <= 32; m <<= 1) cp += __shfl_xor(cp, m);
        __syncthreads();
        float* wsum = (float*)cand;
        if (lane == 0) wsum[wid] = cp;
        __syncthreads();
        if (tid == 0) {
            float t = (wsum[0] + wsum[1]) + (wsum[2] + wsum[3]);
            atomicAdd(out + (size_t)NPTS * DDIM + NPTS,
                      t * (1.0f / ((float)NPTS * (float)DDIM)));
        }
    }
}

// ---------------------------------------------------------------------------
extern "C" void kernel_launch(void* const* d_in, const int* in_sizes, int n_in,
                              void* d_out, int out_size, void* d_ws, size_t ws_size,
                              hipStream_t stream) {
    const float* x    = (const float*)d_in[0];
    const float* cb   = (const float*)d_in[1];
    const float* linw = (const float*)d_in[2];
    const float* linb = (const float*)d_in[3];
    float* out    = (float*)d_out;
    float* norms  = (float*)d_ws;                        // 3072 f
    float* ascore = norms + 4096;                        // 3072 f
    f16*   cb16   = (f16*)((char*)d_ws + 32768);         // 786432 B
    const size_t need = 32768 + (size_t)NVQ * KCODES * DDIM * 2;

    zero_commit_kernel<<<1, 1, 0, stream>>>(out + (size_t)NPTS * DDIM + NPTS);
    norms_kernel<<<NVQ * KCODES, 64, 0, stream>>>(cb, norms, ascore);

    if (ws_size >= need) {
        preconv_kernel<<<(NVQ * KCODES * DDIM) / (256 * 8), 256, 0, stream>>>(cb, cb16);
        rvq_kernel<true><<<NPTS / TM, BLOCKT, 0, stream>>>(x, cb, cb16, linw, linb,
                                                           norms, ascore, out);
    } else {
        rvq_kernel<false><<<NPTS / TM, BLOCKT, 0, stream>>>(x, cb, cb16, linw, linb,
                                                            norms, ascore, out);
    }
}

// Round 17
// 546.722 us; speedup vs baseline: 3.4423x; 1.1422x over previous
//
#include <hip/hip_runtime.h>
#include <float.h>

typedef _Float16 f16;
typedef f16 f16x8 __attribute__((ext_vector_type(8)));
typedef float f32x4 __attribute__((ext_vector_type(4)));
typedef unsigned int u32;

#define NPTS 262144
#define DDIM 128
#define NVQ 6
#define KCODES 512
#define TM 64
#define BLOCKT 256

#define GLD16(gp, lp)                                                          \
    __builtin_amdgcn_global_load_lds(                                          \
        (const __attribute__((address_space(1))) void*)(gp),                   \
        (__attribute__((address_space(3))) void*)(lp), 16, 0, 0)

__device__ __forceinline__ int swz(int row, int grp) {
    return row * DDIM + ((grp ^ (row & 7)) << 3);
}
__device__ __forceinline__ u32 umin32(u32 a, u32 b) { return a < b ? a : b; }
__device__ __forceinline__ u32 umax32(u32 a, u32 b) { return a > b ? a : b; }

__device__ __forceinline__ f16x8 cvt8(float4 a, float4 b) {
    f16x8 h;
    h[0] = (f16)a.x; h[1] = (f16)a.y; h[2] = (f16)a.z; h[3] = (f16)a.w;
    h[4] = (f16)b.x; h[5] = (f16)b.y; h[6] = (f16)b.z; h[7] = (f16)b.w;
    return h;
}

// ---------------------------------------------------------------------------
__global__ void zero_commit_kernel(float* p) { *p = 0.0f; }

__global__ void norms_kernel(const float* __restrict__ cb, float* __restrict__ norms,
                             float* __restrict__ ascore) {
    int row = blockIdx.x;
    int lane = threadIdx.x;
    const float* r = cb + (size_t)row * DDIM;
    float2 v = *(const float2*)(r + lane * 2);
    float s = v.x * v.x + v.y * v.y;
    #pragma unroll
    for (int m = 32; m >= 1; m >>= 1) s += __shfl_xor(s, m);
    if (lane == 0) { norms[row] = s; ascore[row] = 512.0f - 0.5f * s; }
}

__global__ void preconv_kernel(const float* __restrict__ cb, f16* __restrict__ cb16) {
    size_t base = ((size_t)blockIdx.x * 256 + threadIdx.x) * 8;
    float4 a = *(const float4*)(cb + base);
    float4 b = *(const float4*)(cb + base + 4);
    *(f16x8*)(cb16 + base) = cvt8(a, b);
}

// ---------------------------------------------------------------------------
// Residual VQ — r16 numerics EXACTLY (PASSING, absmax 5.421875), restructured
// for 4 blocks/CU (4 waves/SIMD):
//  - ebuf SINGLE-buffered (16KB; LDS total 36.9KB -> 4 blocks). Overwrite is
//    safe after `s_waitcnt lgkmcnt(0)` (all ds_reads of the tile returned).
//    Next-chunk GLD16s issue before the epilogue -> latency covered by
//    epilogue + loopback + 4-wave TLP.
//  - Bf NOT cached per stage: read per (ks,j) inside the chunk loop. The
//    in-loop "memory"-clobber fences keep the reads in-loop (no 64-reg
//    hoisted cache) -> live set ~98 fits waves_per_eu(4,4) budget (128)
//    spill-free. Values/order identical whether or not hoisted.
//  - cross-stage chunk-0 prefetch kept (issued in ch==7 slot, lands under
//    the merge/rescue tail).
// FP ORDER FROZEN: for ks {for j} MFMA chain, ainit = ascore fold (r16),
// keys/butterfly/merge/rescue byte-identical (r8/r9 lesson: no reorder).
template<bool PRE>
__global__ __launch_bounds__(BLOCKT)
__attribute__((amdgpu_waves_per_eu(4, 4)))
void rvq_kernel(const float* __restrict__ x, const float* __restrict__ cb,
                const f16* __restrict__ cb16, const float* __restrict__ W,
                const float* __restrict__ bias, const float* __restrict__ norms,
                const float* __restrict__ ascore, float* __restrict__ out) {
    __shared__ f16   rh[TM * DDIM];     // 16 KB residual/y fp16, swizzled
    __shared__ f16   ebuf[4][2048];     // 16 KB wave-private A buffer (single)
    __shared__ float as_lds[KCODES];    // 2 KB ascore slice (current stage)
    __shared__ uint2 cand[4][TM];       // 2 KB per-wave top2 keys per point

    const int tid  = threadIdx.x;
    const int wid  = tid >> 6;
    const int lane = tid & 63;
    const int g    = lane >> 4;      // k-group 0..3
    const int li   = lane & 15;      // row/col within 16-tile
    const int p_own = tid >> 2;      // owned point 0..63
    const int q     = tid & 3;       // owned d-quarter
    const int p0    = blockIdx.x * TM;

    const int srow = (lane >> 4);    // staging row group
    const int sgrp = lane & 15;      // staging 16B group

    // ---- x -> r (regs) and rh (fp16 LDS) ----
    float r[32];
    {
        const float* xs = x + (size_t)(p0 + p_own) * DDIM + q * 32;
        #pragma unroll
        for (int k = 0; k < 8; ++k) {
            float4 v = *(const float4*)(xs + 4 * k);
            r[4*k] = v.x; r[4*k+1] = v.y; r[4*k+2] = v.z; r[4*k+3] = v.w;
        }
    }
    #pragma unroll
    for (int k = 0; k < 4; ++k) {
        f16x8 h;
        #pragma unroll
        for (int m = 0; m < 8; ++m) h[m] = (f16)r[8*k+m];
        *(f16x8*)&rh[swz(p_own, q * 4 + k)] = h;
    }

    // ---- pre-loop: as_lds for s=0 + stage-0 chunk-0 A-tile ----
    as_lds[tid]       = ascore[tid];
    as_lds[tid + 256] = ascore[tid + 256];
    if constexpr (PRE) {
        const char* gsb0 = (const char*)cb16 + ((size_t)16 * wid) * (DDIM * 2);
        char* lb = (char*)&ebuf[wid][0];
        #pragma unroll
        for (int it = 0; it < 4; ++it) {
            int row = it * 4 + srow;
            GLD16(gsb0 + row * 256 + ((sgrp ^ (row & 7)) << 4), lb + it * 1024);
        }
    }
    __syncthreads();

    float commit_part = 0.0f;

    #pragma unroll 1
    for (int s = 0; s < NVQ; ++s) {
        u32 k1[4], k2[4];
        #pragma unroll
        for (int j = 0; j < 4; ++j) { k1[j] = 0u; k2[j] = 0u; }

        if constexpr (PRE) {
            const char* gsb = (const char*)cb16 +
                              ((size_t)s * KCODES + 16 * wid) * (DDIM * 2);
            char* lb = (char*)&ebuf[wid][0];

            #pragma unroll 1
            for (int ch = 0; ch < 8; ++ch) {
                asm volatile("s_waitcnt vmcnt(0)" ::: "memory");  // tile ready

                float4 as4 = *(const float4*)&as_lds[ch * 64 + 16 * wid + 4 * g];
                f32x4 ainit;
                ainit[0] = as4.x; ainit[1] = as4.y; ainit[2] = as4.z; ainit[3] = as4.w;
                f32x4 acc[4];
                #pragma unroll
                for (int j = 0; j < 4; ++j) acc[j] = ainit;

                __builtin_amdgcn_s_setprio(1);
                #pragma unroll
                for (int ks = 0; ks < 4; ++ks) {
                    f16x8 Af = *(const f16x8*)(lb + li * 256 +
                                               (((ks * 4 + g) ^ (li & 7)) << 4));
                    #pragma unroll
                    for (int j = 0; j < 4; ++j) {
                        f16x8 Bf = *(const f16x8*)&rh[swz(16 * j + li, ks * 4 + g)];
                        acc[j] = __builtin_amdgcn_mfma_f32_16x16x32_f16(Af, Bf, acc[j], 0, 0, 0);
                    }
                }
                __builtin_amdgcn_s_setprio(0);

                // all ds_reads of this tile retired -> buffer reusable
                asm volatile("s_waitcnt lgkmcnt(0)" ::: "memory");
                if (ch < 7) {
                    #pragma unroll
                    for (int it = 0; it < 4; ++it) {
                        int row = it * 4 + srow;
                        GLD16(gsb + (size_t)(ch + 1) * 16384 + row * 256 +
                                  ((sgrp ^ (row & 7)) << 4),
                              lb + it * 1024);
                    }
                } else if (s < NVQ - 1) {
                    // cross-stage prologue: s+1 chunk 0; lands under tail
                    const char* gsbn = gsb + (size_t)KCODES * DDIM * 2;
                    #pragma unroll
                    for (int it = 0; it < 4; ++it) {
                        int row = it * 4 + srow;
                        GLD16(gsbn + row * 256 + ((sgrp ^ (row & 7)) << 4),
                              lb + it * 1024);
                    }
                }

                const int invc = 511 - (ch * 64 + 16 * wid + 4 * g);
                #pragma unroll
                for (int j = 0; j < 4; ++j) {
                    #pragma unroll
                    for (int reg = 0; reg < 4; ++reg) {
                        u32 key = (__float_as_uint(acc[j][reg]) & 0xFFFFFE00u) |
                                  (u32)(invc - reg);
                        u32 lo = umin32(k1[j], key);
                        k1[j] = umax32(k1[j], key);
                        k2[j] = umax32(k2[j], lo);
                    }
                }
            }
        } else {
            // fallback: direct-global path (fp32 cvt), Bf cached per stage
            f16x8 Bf[4][4];
            #pragma unroll
            for (int j = 0; j < 4; ++j)
                #pragma unroll
                for (int ks = 0; ks < 4; ++ks)
                    Bf[j][ks] = *(const f16x8*)&rh[swz(16 * j + li, ks * 4 + g)];
            const float* Ab32 = cb + ((size_t)s * KCODES + 16 * wid + li) * DDIM + g * 8;
            #pragma unroll 2
            for (int ch = 0; ch < 8; ++ch) {
                float4 as4 = *(const float4*)&as_lds[ch * 64 + 16 * wid + 4 * g];
                f32x4 ainit;
                ainit[0] = as4.x; ainit[1] = as4.y; ainit[2] = as4.z; ainit[3] = as4.w;
                f32x4 acc[4];
                #pragma unroll
                for (int j = 0; j < 4; ++j) acc[j] = ainit;
                #pragma unroll
                for (int ks = 0; ks < 4; ++ks) {
                    const float* ap = Ab32 + (size_t)ch * 64 * DDIM + ks * 32;
                    f16x8 Af = cvt8(*(const float4*)ap, *(const float4*)(ap + 4));
                    #pragma unroll
                    for (int j = 0; j < 4; ++j)
                        acc[j] = __builtin_amdgcn_mfma_f32_16x16x32_f16(Af, Bf[j][ks], acc[j], 0, 0, 0);
                }
                const int invc = 511 - (ch * 64 + 16 * wid + 4 * g);
                #pragma unroll
                for (int j = 0; j < 4; ++j) {
                    #pragma unroll
                    for (int reg = 0; reg < 4; ++reg) {
                        u32 key = (__float_as_uint(acc[j][reg]) & 0xFFFFFE00u) |
                                  (u32)(invc - reg);
                        u32 lo = umin32(k1[j], key);
                        k1[j] = umax32(k1[j], key);
                        k2[j] = umax32(k2[j], lo);
                    }
                }
            }
        }

        // ---- in-wave top-2 butterfly across k-groups (lanes xor 16, 32) ----
        #pragma unroll
        for (int m = 16; m <= 32; m <<= 1) {
            #pragma unroll
            for (int j = 0; j < 4; ++j) {
                u32 o1 = (u32)__shfl_xor((int)k1[j], m);
                u32 o2 = (u32)__shfl_xor((int)k2[j], m);
                u32 lo = umin32(k1[j], o1);
                k1[j] = umax32(k1[j], o1);
                k2[j] = umax32(umax32(k2[j], o2), lo);
            }
        }
        if (lane < 16) {
            #pragma unroll
            for (int j = 0; j < 4; ++j)
                cand[wid][16 * j + li] = make_uint2(k1[j], k2[j]);
        }
        __syncthreads();   // SYNC-B: cand ready; all waves past chunk loop

        // ---- tail: ascore prefetch for s+1 (latency hides under rescue) ----
        float as_n0 = 0.0f, as_n1 = 0.0f;
        if (s < NVQ - 1) {
            as_n0 = ascore[(s + 1) * KCODES + tid];
            as_n1 = ascore[(s + 1) * KCODES + tid + 256];
        }

        // ---- cross-wave merge, redundantly in every thread ----
        uint2 v0 = cand[0][p_own];
        u32 m1 = v0.x, m2 = v0.y;
        #pragma unroll
        for (int w = 1; w < 4; ++w) {
            uint2 vv = cand[w][p_own];
            u32 lo = umin32(m1, vv.x);
            m1 = umax32(m1, vv.x);
            m2 = umax32(umax32(m2, vv.y), lo);
        }
        int c1 = 511 - (int)(m1 & 0x1FFu);
        int c2 = 511 - (int)(m2 & 0x1FFu);

        // ---- exact fp32 rescue on top-2 (registers only) ----
        const float* E1 = cb + (size_t)(s * KCODES + c1) * DDIM + q * 32;
        const float* E2 = cb + (size_t)(s * KCODES + c2) * DDIM + q * 32;
        float dot1 = 0.0f, dot2 = 0.0f;
        #pragma unroll
        for (int k = 0; k < 8; ++k) {
            float4 a = *(const float4*)(E1 + 4 * k);
            dot1 += a.x * r[4*k] + a.y * r[4*k+1] + a.z * r[4*k+2] + a.w * r[4*k+3];
        }
        #pragma unroll
        for (int k = 0; k < 8; ++k) {
            float4 a = *(const float4*)(E2 + 4 * k);
            dot2 += a.x * r[4*k] + a.y * r[4*k+1] + a.z * r[4*k+2] + a.w * r[4*k+3];
        }
        dot1 += __shfl_xor(dot1, 1); dot1 += __shfl_xor(dot1, 2);
        dot2 += __shfl_xor(dot2, 1); dot2 += __shfl_xor(dot2, 2);
        float d1e = fmaf(-2.0f, dot1, norms[s * KCODES + c1]);
        float d2e = fmaf(-2.0f, dot2, norms[s * KCODES + c2]);
        int best = (d2e < d1e || (d2e == d1e && c2 < c1)) ? c2 : c1;

        if (s == 0 && q == 0)
            out[(size_t)NPTS * DDIM + p0 + p_own] = (float)best;

        // ---- exact residual update (regs) + rh rewrite for next stage ----
        {
            const float* Eb = cb + (size_t)(s * KCODES + best) * DDIM + q * 32;
            float cp = 0.0f;
            #pragma unroll
            for (int k = 0; k < 8; ++k) {
                float4 e = *(const float4*)(Eb + 4 * k);
                r[4*k]   -= e.x; r[4*k+1] -= e.y; r[4*k+2] -= e.z; r[4*k+3] -= e.w;
                cp += r[4*k]*r[4*k] + r[4*k+1]*r[4*k+1] + r[4*k+2]*r[4*k+2] + r[4*k+3]*r[4*k+3];
            }
            if (s == 0) commit_part = cp;
        }
        if (s < NVQ - 1) {
            #pragma unroll
            for (int k = 0; k < 4; ++k) {
                f16x8 h;
                #pragma unroll
                for (int m = 0; m < 8; ++m) h[m] = (f16)r[8*k+m];
                *(f16x8*)&rh[swz(p_own, q * 4 + k)] = h;
            }
            // as_lds refill for s+1 (safe: all reads finished before SYNC-B)
            as_lds[tid]       = as_n0;
            as_lds[tid + 256] = as_n1;
        }
        __syncthreads();   // SYNC-C: rh + as_lds published for stage s+1
    }

    // ---- y = x - r_final -> rh ----
    {
        const float* xs = x + (size_t)(p0 + p_own) * DDIM + q * 32;
        #pragma unroll
        for (int k = 0; k < 4; ++k) {
            float4 a = *(const float4*)(xs + 8 * k);
            float4 b = *(const float4*)(xs + 8 * k + 4);
            f16x8 h;
            h[0]=(f16)(a.x - r[8*k+0]); h[1]=(f16)(a.y - r[8*k+1]);
            h[2]=(f16)(a.z - r[8*k+2]); h[3]=(f16)(a.w - r[8*k+3]);
            h[4]=(f16)(b.x - r[8*k+4]); h[5]=(f16)(b.y - r[8*k+5]);
            h[6]=(f16)(b.z - r[8*k+6]); h[7]=(f16)(b.w - r[8*k+7]);
            *(f16x8*)&rh[swz(p_own, q * 4 + k)] = h;
        }
    }
    __syncthreads();

    // ---- final linear: out = y @ W^T + b (W rows streamed from global) ----
    {
        f16x8 Yf[4][4];
        #pragma unroll
        for (int j = 0; j < 4; ++j)
            #pragma unroll
            for (int ks = 0; ks < 4; ++ks)
                Yf[j][ks] = *(const f16x8*)&rh[swz(16 * j + li, ks * 4 + g)];

        #pragma unroll 1
        for (int ch = 0; ch < 2; ++ch) {
            float4 b4 = *(const float4*)(bias + ch * 64 + 16 * wid + 4 * g);
            f32x4 acc[4];
            #pragma unroll
            for (int j = 0; j < 4; ++j) {
                acc[j][0] = b4.x; acc[j][1] = b4.y; acc[j][2] = b4.z; acc[j][3] = b4.w;
            }
            __builtin_amdgcn_s_setprio(1);
            #pragma unroll
            for (int ks = 0; ks < 4; ++ks) {
                const float* wp = W + (size_t)(ch * 64 + 16 * wid + li) * DDIM + ks * 32 + g * 8;
                f16x8 Af = cvt8(*(const float4*)wp, *(const float4*)(wp + 4));
                #pragma unroll
                for (int j = 0; j < 4; ++j)
                    acc[j] = __builtin_amdgcn_mfma_f32_16x16x32_f16(Af, Yf[j][ks], acc[j], 0, 0, 0);
            }
            __builtin_amdgcn_s_setprio(0);
            int obase = ch * 64 + 16 * wid + 4 * g;
            #pragma unroll
            for (int j = 0; j < 4; ++j)
                *(float4*)(out + (size_t)(p0 + 16 * j + li) * DDIM + obase) =
                    make_float4(acc[j][0], acc[j][1], acc[j][2], acc[j][3]);
        }
    }

    // ---- commit loss: wave shuffle-reduce + block atomic ----
    {
        float cp = commit_part;
        #pragma unroll
        for (int m = 1; m <= 32; m <<= 1) cp += __shfl_xor(cp, m);
        __syncthreads();
        float* wsum = (float*)cand;
        if (lane == 0) wsum[wid] = cp;
        __syncthreads();
        if (tid == 0) {
            float t = (wsum[0] + wsum[1]) + (wsum[2] + wsum[3]);
            atomicAdd(out + (size_t)NPTS * DDIM + NPTS,
                      t * (1.0f / ((float)NPTS * (float)DDIM)));
        }
    }
}

// ---------------------------------------------------------------------------
extern "C" void kernel_launch(void* const* d_in, const int* in_sizes, int n_in,
                              void* d_out, int out_size, void* d_ws, size_t ws_size,
                              hipStream_t stream) {
    const float* x    = (const float*)d_in[0];
    const float* cb   = (const float*)d_in[1];
    const float* linw = (const float*)d_in[2];
    const float* linb = (const float*)d_in[3];
    float* out    = (float*)d_out;
    float* norms  = (float*)d_ws;                        // 3072 f
    float* ascore = norms + 4096;                        // 3072 f
    f16*   cb16   = (f16*)((char*)d_ws + 32768);         // 786432 B
    const size_t need = 32768 + (size_t)NVQ * KCODES * DDIM * 2;

    zero_commit_kernel<<<1, 1, 0, stream>>>(out + (size_t)NPTS * DDIM + NPTS);
    norms_kernel<<<NVQ * KCODES, 64, 0, stream>>>(cb, norms, ascore);

    if (ws_size >= need) {
        preconv_kernel<<<(NVQ * KCODES * DDIM) / (256 * 8), 256, 0, stream>>>(cb, cb16);
        rvq_kernel<true><<<NPTS / TM, BLOCKT, 0, stream>>>(x, cb, cb16, linw, linb,
                                                           norms, ascore, out);
    } else {
        rvq_kernel<false><<<NPTS / TM, BLOCKT, 0, stream>>>(x, cb, cb16, linw, linb,
                                                            norms, ascore, out);
    }
}